// Round 14
// baseline (428.898 us; speedup 1.0000x reference)
//
#include <hip/hip_runtime.h>

#define NN 100000
#define NE 1600000
#define IN_DIM 32
#define DD 64
#define NG 128
#define BN_EPS 1e-5f
#define AGG_BLOCKS 2048

typedef unsigned short ushort_t;
typedef unsigned int uint_t;

__device__ __forceinline__ ushort_t f2bf(float f) {
    uint_t u = __float_as_uint(f);
    u = (u + 0x7FFFu + ((u >> 16) & 1u)) >> 16;  // RNE
    return (ushort_t)u;
}
__device__ __forceinline__ uint_t pack2(float a, float b) {
    return (uint_t)f2bf(a) | ((uint_t)f2bf(b) << 16);
}
__device__ __forceinline__ float bflo(uint_t u) { return __uint_as_float(u << 16); }
__device__ __forceinline__ float bfhi(uint_t u) { return __uint_as_float(u & 0xFFFF0000u); }

// ---------------- init: zero cnt/cursor, pool, sums1+sums2 ----------------
__global__ void init_k(int* __restrict__ ints, long n_ints, float* __restrict__ pool,
                       float* __restrict__ sums) {
    long i = (long)blockIdx.x * blockDim.x + threadIdx.x;
    if (i < n_ints) ints[i] = 0;
    if (i < (long)NG * DD) pool[i] = 0.f;
    if (i < 256) sums[i] = 0.f;
}

// ---- degree count + per-edge rank (one atomic pass; rank written coalesced) ----
__global__ void deg_rank(const int* __restrict__ dst, int* __restrict__ cnt,
                         int* __restrict__ rank) {
    int e = blockIdx.x * blockDim.x + threadIdx.x;
    if (e < NE) rank[e] = atomicAdd(&cnt[dst[e]], 1);
}

// start[n] = block-local exclusive scan + atomic base; dis[n] = rsqrt(deg+1)
__global__ __launch_bounds__(256) void alloc_k(const int* __restrict__ cnt,
                                               int* __restrict__ start,
                                               int* __restrict__ cursor,
                                               float* __restrict__ dis) {
    __shared__ int ls[256];
    __shared__ int base_s;
    int t = threadIdx.x;
    long n = (long)blockIdx.x * 256 + t;
    int v = (n < NN) ? cnt[n] : 0;
    ls[t] = v;
    __syncthreads();
    for (int off = 1; off < 256; off <<= 1) {
        int y = (t >= off) ? ls[t - off] : 0;
        __syncthreads();
        ls[t] += y;
        __syncthreads();
    }
    if (t == 0) base_s = atomicAdd(cursor, ls[255]);
    __syncthreads();
    if (n < NN) {
        start[n] = base_s + ls[t] - v;
        dis[n] = rsqrtf((float)v + 1.0f);
    }
}

// ---- fused: blocks [0, nbE) fill ep; blocks [nbE, nbE+nbN) compute hw1 ----
// fill: ep[start[t]+rank[e]] = src(17b) | norm15 << 17   (atomic-free)
// mm1:  hw1 = x @ (W_embed@W1), Weff built per block in LDS, bf16 rows out
__global__ __launch_bounds__(256) void fill_mm1_k(const int* __restrict__ src,
                                                  const int* __restrict__ dstp,
                                                  const int* __restrict__ rank,
                                                  const float* __restrict__ dis,
                                                  const int* __restrict__ start,
                                                  uint_t* __restrict__ ep,
                                                  const float* __restrict__ x,
                                                  const float* __restrict__ We,
                                                  const float* __restrict__ W1,
                                                  ushort_t* __restrict__ hwb,
                                                  int nbE) {
    __shared__ float W1s[DD * DD];
    __shared__ float Ws[IN_DIM * DD];
    int t = threadIdx.x;

    if ((int)blockIdx.x < nbE) {
        long e = (long)blockIdx.x * 256 + t;
        if (e < NE) {
            int s = src[e], d = dstp[e];
            float nm = dis[s] * dis[d];
            uint_t nb = (__float_as_uint(nm) + 0x8000u) >> 16;
            ep[start[d] + rank[e]] = (uint_t)s | ((nb & 0x7FFFu) << 17);
        }
        return;
    }

    // ---- mm1 part ----
    int bid = (int)blockIdx.x - nbE;
    for (int i = t; i < DD * DD; i += 256) W1s[i] = W1[i];
    __syncthreads();
    for (int idx = t; idx < IN_DIM * DD; idx += 256) {
        int i = idx >> 6, j = idx & 63;
        float s = 0.f;
#pragma unroll
        for (int k = 0; k < DD; ++k) s += We[i * DD + k] * W1s[k * DD + j];
        Ws[idx] = s;
    }
    __syncthreads();
    long n = (long)bid * 256 + t;
    if (n >= NN) return;
    float acc[DD];
#pragma unroll
    for (int d = 0; d < DD; ++d) acc[d] = 0.f;
    const float4* xr = (const float4*)(x + n * IN_DIM);
#pragma unroll
    for (int k4 = 0; k4 < IN_DIM / 4; ++k4) {
        float4 xv = xr[k4];
        const float* xp = (const float*)&xv;
#pragma unroll
        for (int kk = 0; kk < 4; ++kk) {
            float v = xp[kk];
            const float4* w4 = (const float4*)&Ws[(k4 * 4 + kk) * DD];
#pragma unroll
            for (int d4 = 0; d4 < DD / 4; ++d4) {
                float4 wv = w4[d4];
                acc[4 * d4 + 0] += v * wv.x;
                acc[4 * d4 + 1] += v * wv.y;
                acc[4 * d4 + 2] += v * wv.z;
                acc[4 * d4 + 3] += v * wv.w;
            }
        }
    }
    uint4* o = (uint4*)(hwb + n * DD);
#pragma unroll
    for (int d8 = 0; d8 < DD / 8; ++d8) {
        uint4 pk;
        pk.x = pack2(acc[8 * d8 + 0], acc[8 * d8 + 1]);
        pk.y = pack2(acc[8 * d8 + 2], acc[8 * d8 + 3]);
        pk.z = pack2(acc[8 * d8 + 4], acc[8 * d8 + 5]);
        pk.w = pack2(acc[8 * d8 + 6], acc[8 * d8 + 7]);
        o[d8] = pk;
    }
}

// ------ hw2 = BN1(agg1_bf16)+ReLU @ W2 -> bf16 rows ------
__global__ __launch_bounds__(256) void mm2_bn_k(const ushort_t* __restrict__ aggb,
                                                const float* __restrict__ sums,
                                                const float* __restrict__ g,
                                                const float* __restrict__ bt,
                                                const float* __restrict__ W,
                                                ushort_t* __restrict__ hwb) {
    __shared__ float Ws[DD * DD];
    __shared__ float mu_s[DD], sc_s[DD], bt_s[DD];
    int t = threadIdx.x;
    for (int i = t; i < DD * DD; i += 256) Ws[i] = W[i];
    if (t < DD) {
        const float inv_n = 1.0f / (float)NN;
        float mu = sums[t] * inv_n;
        float var = sums[64 + t] * inv_n - mu * mu;
        mu_s[t] = mu;
        sc_s[t] = g[t] * rsqrtf(var + BN_EPS);
        bt_s[t] = bt[t];
    }
    __syncthreads();
    long n = (long)blockIdx.x * 256 + t;
    if (n >= NN) return;
    float acc[DD];
#pragma unroll
    for (int d = 0; d < DD; ++d) acc[d] = 0.f;
    const uint4* ar = (const uint4*)(aggb + n * DD);
#pragma unroll
    for (int k8 = 0; k8 < DD / 8; ++k8) {
        uint4 av = ar[k8];
        float hv[8];
        hv[0] = bflo(av.x); hv[1] = bfhi(av.x);
        hv[2] = bflo(av.y); hv[3] = bfhi(av.y);
        hv[4] = bflo(av.z); hv[5] = bfhi(av.z);
        hv[6] = bflo(av.w); hv[7] = bfhi(av.w);
#pragma unroll
        for (int kk = 0; kk < 8; ++kk) {
            int k = k8 * 8 + kk;
            float h = fmaxf((hv[kk] - mu_s[k]) * sc_s[k] + bt_s[k], 0.f);
            const float4* w4 = (const float4*)&Ws[k * DD];
#pragma unroll
            for (int d4 = 0; d4 < DD / 4; ++d4) {
                float4 wv = w4[d4];
                acc[4 * d4 + 0] += h * wv.x;
                acc[4 * d4 + 1] += h * wv.y;
                acc[4 * d4 + 2] += h * wv.z;
                acc[4 * d4 + 3] += h * wv.w;
            }
        }
    }
    uint4* o = (uint4*)(hwb + n * DD);
#pragma unroll
    for (int d8 = 0; d8 < DD / 8; ++d8) {
        uint4 pk;
        pk.x = pack2(acc[8 * d8 + 0], acc[8 * d8 + 1]);
        pk.y = pack2(acc[8 * d8 + 2], acc[8 * d8 + 3]);
        pk.z = pack2(acc[8 * d8 + 4], acc[8 * d8 + 5]);
        pk.w = pack2(acc[8 * d8 + 6], acc[8 * d8 + 7]);
        o[d8] = pk;
    }
}

// ------- gather-aggregate: 8 lanes/row uint4, 32 edges in flight, shfl reduce -------
// agg rows written bf16; BN stats (f32, pre-rounding) -> sums via LDS + atomics
__global__ __launch_bounds__(256) void gcn_agg(const ushort_t* __restrict__ hwb,
                                               const float* __restrict__ dis,
                                               const int* __restrict__ cnt,
                                               const int* __restrict__ start,
                                               const uint_t* __restrict__ ep,
                                               const float* __restrict__ bias,
                                               ushort_t* __restrict__ aggb,
                                               float* __restrict__ sums) {
    int t = threadIdx.x;
    int w = t >> 6;
    int lane = t & 63;
    int j = lane >> 3;
    int c = lane & 7;
    float selfmask = (j == 0) ? 1.f : 0.f;

    __shared__ float ls[4][128];
    for (int k = t; k < 512; k += 256) ((float*)ls)[k] = 0.f;
    __syncthreads();

    float bs[8];
#pragma unroll
    for (int k = 0; k < 8; ++k) bs[k] = bias[8 * c + k];

    for (long n = (long)blockIdx.x * 4 + w; n < NN; n += (long)gridDim.x * 4) {
        int rs = start[n];
        int ce = cnt[n];
        float sn = dis[n];
        float sq = sn * sn;

        uint4 sv = ((const uint4*)(hwb + (long)n * DD))[c];
        float acc[8];
        acc[0] = selfmask * (bflo(sv.x) * sq + bs[0]);
        acc[1] = selfmask * (bfhi(sv.x) * sq + bs[1]);
        acc[2] = selfmask * (bflo(sv.y) * sq + bs[2]);
        acc[3] = selfmask * (bfhi(sv.y) * sq + bs[3]);
        acc[4] = selfmask * (bflo(sv.z) * sq + bs[4]);
        acc[5] = selfmask * (bfhi(sv.z) * sq + bs[5]);
        acc[6] = selfmask * (bflo(sv.w) * sq + bs[6]);
        acc[7] = selfmask * (bfhi(sv.w) * sq + bs[7]);

        for (int i = 0; i < ce; i += 32) {
            int i0 = i + j, i1 = i + 8 + j, i2 = i + 16 + j, i3 = i + 24 + j;
            uint_t u0 = (i0 < ce) ? ep[rs + i0] : 0u;
            uint_t u1 = (i1 < ce) ? ep[rs + i1] : 0u;
            uint_t u2 = (i2 < ce) ? ep[rs + i2] : 0u;
            uint_t u3 = (i3 < ce) ? ep[rs + i3] : 0u;
            uint4 q0 = ((const uint4*)(hwb + (long)(u0 & 0x1FFFF) * DD))[c];
            uint4 q1 = ((const uint4*)(hwb + (long)(u1 & 0x1FFFF) * DD))[c];
            uint4 q2 = ((const uint4*)(hwb + (long)(u2 & 0x1FFFF) * DD))[c];
            uint4 q3 = ((const uint4*)(hwb + (long)(u3 & 0x1FFFF) * DD))[c];
            float n0 = __uint_as_float((u0 >> 17) << 16);
            float n1 = __uint_as_float((u1 >> 17) << 16);
            float n2 = __uint_as_float((u2 >> 17) << 16);
            float n3 = __uint_as_float((u3 >> 17) << 16);
            acc[0] += bflo(q0.x) * n0; acc[1] += bfhi(q0.x) * n0;
            acc[2] += bflo(q0.y) * n0; acc[3] += bfhi(q0.y) * n0;
            acc[4] += bflo(q0.z) * n0; acc[5] += bfhi(q0.z) * n0;
            acc[6] += bflo(q0.w) * n0; acc[7] += bfhi(q0.w) * n0;
            acc[0] += bflo(q1.x) * n1; acc[1] += bfhi(q1.x) * n1;
            acc[2] += bflo(q1.y) * n1; acc[3] += bfhi(q1.y) * n1;
            acc[4] += bflo(q1.z) * n1; acc[5] += bfhi(q1.z) * n1;
            acc[6] += bflo(q1.w) * n1; acc[7] += bfhi(q1.w) * n1;
            acc[0] += bflo(q2.x) * n2; acc[1] += bfhi(q2.x) * n2;
            acc[2] += bflo(q2.y) * n2; acc[3] += bfhi(q2.y) * n2;
            acc[4] += bflo(q2.z) * n2; acc[5] += bfhi(q2.z) * n2;
            acc[6] += bflo(q2.w) * n2; acc[7] += bfhi(q2.w) * n2;
            acc[0] += bflo(q3.x) * n3; acc[1] += bfhi(q3.x) * n3;
            acc[2] += bflo(q3.y) * n3; acc[3] += bfhi(q3.y) * n3;
            acc[4] += bflo(q3.z) * n3; acc[5] += bfhi(q3.z) * n3;
            acc[6] += bflo(q3.w) * n3; acc[7] += bfhi(q3.w) * n3;
        }

#pragma unroll
        for (int m = 8; m < 64; m <<= 1) {
#pragma unroll
            for (int k = 0; k < 8; ++k) acc[k] += __shfl_xor(acc[k], m, 64);
        }

        if (j == 0) {
            uint4 pk;
            pk.x = pack2(acc[0], acc[1]);
            pk.y = pack2(acc[2], acc[3]);
            pk.z = pack2(acc[4], acc[5]);
            pk.w = pack2(acc[6], acc[7]);
            ((uint4*)(aggb + (long)n * DD))[c] = pk;
#pragma unroll
            for (int k = 0; k < 8; ++k) {
                ls[w][8 * c + k] += acc[k];
                ls[w][64 + 8 * c + k] += acc[k] * acc[k];
            }
        }
    }

    __syncthreads();
    if (t < 128) {
        float a = ls[0][t] + ls[1][t] + ls[2][t] + ls[3][t];
        atomicAdd(&sums[t], a);
    }
}

// ---------- BN2 apply (bf16 agg in) + write h + global_add_pool ----------
__global__ __launch_bounds__(256) void bn_pool(const ushort_t* __restrict__ aggb,
                                               const float* __restrict__ sums,
                                               const float* __restrict__ g,
                                               const float* __restrict__ bt,
                                               const int* __restrict__ batch,
                                               float* __restrict__ out,
                                               float* __restrict__ pool) {
    int t = threadIdx.x;
    int d = t & 63, rq = t >> 6;
    const float inv_n = 1.0f / (float)NN;
    float mu = sums[d] * inv_n;
    float var = sums[64 + d] * inv_n - mu * mu;
    float sc = g[d] * rsqrtf(var + BN_EPS);
    float bd = bt[d];
    long base = (long)blockIdx.x * 256;
    float acc = 0.f;
    int cur = -1;
    for (int i = 0; i < 64; ++i) {
        long r = base + rq + 4 * i;
        if (r >= NN) break;
        int b = batch[r];
        float av = __uint_as_float(((uint_t)aggb[r * DD + d]) << 16);
        float v = (av - mu) * sc + bd;
        out[r * DD + d] = v;
        if (b != cur) {
            if (cur >= 0) atomicAdd(&pool[(long)cur * DD + d], acc);
            acc = 0.f;
            cur = b;
        }
        acc += v;
    }
    if (cur >= 0) atomicAdd(&pool[(long)cur * DD + d], acc);
}

extern "C" void kernel_launch(void* const* d_in, const int* in_sizes, int n_in,
                              void* d_out, int out_size, void* d_ws, size_t ws_size,
                              hipStream_t stream) {
    const float* x = (const float*)d_in[0];
    const int* ei = (const int*)d_in[1];
    const int* batch = (const int*)d_in[2];
    const float* W_embed = (const float*)d_in[3];
    const float* W1 = (const float*)d_in[4];
    const float* b1 = (const float*)d_in[5];
    const float* g1 = (const float*)d_in[6];
    const float* bt1 = (const float*)d_in[7];
    const float* W2 = (const float*)d_in[8];
    const float* b2 = (const float*)d_in[9];
    const float* g2 = (const float*)d_in[10];
    const float* bt2 = (const float*)d_in[11];

    const int* src = ei;
    const int* dst = ei + NE;

    float* out = (float*)d_out;         // h: N*DD
    float* pool = out + (long)NN * DD;  // h_pool: NG*DD

    const long ND = (long)NN * DD;

    // workspace layout (cnt,cursor contiguous for single zero pass)
    char* w = (char*)d_ws;
    int* cnt = (int*)w;           w += sizeof(int) * NN;
    int* cursor = (int*)w;        w += sizeof(int) * 4;
    int* start = (int*)w;         w += sizeof(int) * NN;
    float* dis = (float*)w;       w += sizeof(float) * NN;
    float* sums1 = (float*)w;     w += sizeof(float) * 128;  // sums1+sums2 contiguous
    float* sums2 = (float*)w;     w += sizeof(float) * 128;
    int* rank = (int*)w;          w += sizeof(int) * NE;
    uint_t* ep = (uint_t*)w;      w += sizeof(uint_t) * NE;
    ushort_t* hwb = (ushort_t*)w; w += sizeof(ushort_t) * ND;
    ushort_t* agg1b = (ushort_t*)w; w += sizeof(ushort_t) * ND;
    ushort_t* agg2b = (ushort_t*)w; /* += sizeof(ushort_t) * ND */

    dim3 blk(256);
    const int nbN = (NN + 255) / 256;
    const int nbE = (NE + 255) / 256;
    const long n_ints = (long)NN + 4;

    // ---- CSR build + norms (single atomic pass; fill fused with mm1) ----
    init_k<<<dim3((int)((n_ints + 255) / 256)), blk, 0, stream>>>(cnt, n_ints, pool, sums1);
    deg_rank<<<dim3(nbE), blk, 0, stream>>>(dst, cnt, rank);
    alloc_k<<<dim3(nbN), blk, 0, stream>>>(cnt, start, cursor, dis);

    // ---- fill ep ∥ hw1 = x @ (W_embed @ W1) ----
    fill_mm1_k<<<dim3(nbE + nbN), blk, 0, stream>>>(src, dst, rank, dis, start, ep,
                                                    x, W_embed, W1, hwb, nbE);

    // ---- layer 1 (agg -> bf16, stats -> sums1) ----
    gcn_agg<<<dim3(AGG_BLOCKS), blk, 0, stream>>>(hwb, dis, cnt, start, ep, b1, agg1b, sums1);

    // ---- BN1+ReLU fused into layer-2 matmul ----
    mm2_bn_k<<<dim3(nbN), blk, 0, stream>>>(agg1b, sums1, g1, bt1, W2, hwb);

    // ---- layer 2 (agg -> bf16, stats -> sums2) ----
    gcn_agg<<<dim3(AGG_BLOCKS), blk, 0, stream>>>(hwb, dis, cnt, start, ep, b2, agg2b, sums2);

    // ---- BN2 + write h + pool ----
    bn_pool<<<dim3(nbN), blk, 0, stream>>>(agg2b, sums2, g2, bt2, batch, out, pool);
}

// Round 15
// 399.074 us; speedup vs baseline: 1.0747x; 1.0747x over previous
//
#include <hip/hip_runtime.h>

#define NN 100000
#define NE 1600000
#define IN_DIM 32
#define DD 64
#define NG 128
#define BN_EPS 1e-5f
#define AGG_BLOCKS 2048

typedef unsigned short ushort_t;
typedef unsigned int uint_t;
typedef __attribute__((ext_vector_type(8))) short bf16x8;
typedef __attribute__((ext_vector_type(4))) float f32x4;

__device__ __forceinline__ ushort_t f2bf(float f) {
    uint_t u = __float_as_uint(f);
    u = (u + 0x7FFFu + ((u >> 16) & 1u)) >> 16;  // RNE
    return (ushort_t)u;
}
__device__ __forceinline__ uint_t pack2(float a, float b) {
    return (uint_t)f2bf(a) | ((uint_t)f2bf(b) << 16);
}
__device__ __forceinline__ float bflo(uint_t u) { return __uint_as_float(u << 16); }
__device__ __forceinline__ float bfhi(uint_t u) { return __uint_as_float(u & 0xFFFF0000u); }

// ---------------- init: zero cnt/cursor, pool, sums1+sums2 ----------------
__global__ void init_k(int* __restrict__ ints, long n_ints, float* __restrict__ pool,
                       float* __restrict__ sums) {
    long i = (long)blockIdx.x * blockDim.x + threadIdx.x;
    if (i < n_ints) ints[i] = 0;
    if (i < (long)NG * DD) pool[i] = 0.f;
    if (i < 256) sums[i] = 0.f;
}

// ---- degree count + per-edge rank (one atomic pass; rank written coalesced) ----
__global__ void deg_rank(const int* __restrict__ dst, int* __restrict__ cnt,
                         int* __restrict__ rank) {
    int e = blockIdx.x * blockDim.x + threadIdx.x;
    if (e < NE) rank[e] = atomicAdd(&cnt[dst[e]], 1);
}

// start[n] = block-local exclusive scan + atomic base; dis[n] = rsqrt(deg+1)
__global__ __launch_bounds__(256) void alloc_k(const int* __restrict__ cnt,
                                               int* __restrict__ start,
                                               int* __restrict__ cursor,
                                               float* __restrict__ dis) {
    __shared__ int ls[256];
    __shared__ int base_s;
    int t = threadIdx.x;
    long n = (long)blockIdx.x * 256 + t;
    int v = (n < NN) ? cnt[n] : 0;
    ls[t] = v;
    __syncthreads();
    for (int off = 1; off < 256; off <<= 1) {
        int y = (t >= off) ? ls[t - off] : 0;
        __syncthreads();
        ls[t] += y;
        __syncthreads();
    }
    if (t == 0) base_s = atomicAdd(cursor, ls[255]);
    __syncthreads();
    if (n < NN) {
        start[n] = base_s + ls[t] - v;
        dis[n] = rsqrtf((float)v + 1.0f);
    }
}

// atomic-free fill: ep[start[t]+rank[e]] = src(17b) | norm15 << 17
__global__ void fill_edges(const int* __restrict__ src, const int* __restrict__ dstp,
                           const int* __restrict__ rank, const float* __restrict__ dis,
                           const int* __restrict__ start, uint_t* __restrict__ ep) {
    int e = blockIdx.x * blockDim.x + threadIdx.x;
    if (e >= NE) return;
    int s = src[e], t = dstp[e];
    float nm = dis[s] * dis[t];
    uint_t nb = (__float_as_uint(nm) + 0x8000u) >> 16;
    ep[start[t] + rank[e]] = (uint_t)s | ((nb & 0x7FFFu) << 17);
}

// -------- hw1 = x @ (W_embed@W1)  (Weff fused per block); bf16 rows --------
__global__ __launch_bounds__(256) void mm1_k(const float* __restrict__ x,
                                             const float* __restrict__ We,
                                             const float* __restrict__ W1,
                                             ushort_t* __restrict__ hwb) {
    __shared__ float W1s[DD * DD];
    __shared__ float Ws[IN_DIM * DD];
    int t = threadIdx.x;
    for (int i = t; i < DD * DD; i += 256) W1s[i] = W1[i];
    __syncthreads();
    for (int idx = t; idx < IN_DIM * DD; idx += 256) {
        int i = idx >> 6, j = idx & 63;
        float s = 0.f;
#pragma unroll
        for (int k = 0; k < DD; ++k) s += We[i * DD + k] * W1s[k * DD + j];
        Ws[idx] = s;
    }
    __syncthreads();
    long n = (long)blockIdx.x * 256 + t;
    if (n >= NN) return;
    float acc[DD];
#pragma unroll
    for (int d = 0; d < DD; ++d) acc[d] = 0.f;
    const float4* xr = (const float4*)(x + n * IN_DIM);
#pragma unroll
    for (int k4 = 0; k4 < IN_DIM / 4; ++k4) {
        float4 xv = xr[k4];
        const float* xp = (const float*)&xv;
#pragma unroll
        for (int kk = 0; kk < 4; ++kk) {
            float v = xp[kk];
            const float4* w4 = (const float4*)&Ws[(k4 * 4 + kk) * DD];
#pragma unroll
            for (int d4 = 0; d4 < DD / 4; ++d4) {
                float4 wv = w4[d4];
                acc[4 * d4 + 0] += v * wv.x;
                acc[4 * d4 + 1] += v * wv.y;
                acc[4 * d4 + 2] += v * wv.z;
                acc[4 * d4 + 3] += v * wv.w;
            }
        }
    }
    uint4* o = (uint4*)(hwb + n * DD);
#pragma unroll
    for (int d8 = 0; d8 < DD / 8; ++d8) {
        uint4 pk;
        pk.x = pack2(acc[8 * d8 + 0], acc[8 * d8 + 1]);
        pk.y = pack2(acc[8 * d8 + 2], acc[8 * d8 + 3]);
        pk.z = pack2(acc[8 * d8 + 4], acc[8 * d8 + 5]);
        pk.w = pack2(acc[8 * d8 + 6], acc[8 * d8 + 7]);
        o[d8] = pk;
    }
}

// ------ hw2 = BN1(agg1_bf16)+ReLU @ W2 via MFMA 16x16x32 bf16 -> bf16 rows ------
// Wave: 16 rows x 64 cols per group; 4 groups/wave; block = 256 rows.
// A frag: lane l holds rows (l&15), k = ks*32 + (l>>4)*8 + j  (8 contiguous bf16)
// B frag: lane l holds cols c*16 + (l&15), same k slice (prestaged in LDS)
// D: col = lane&15, row = (lane>>4)*4 + reg   [m89-verified layout]
__global__ __launch_bounds__(256) void mm2_bn_mfma(const ushort_t* __restrict__ aggb,
                                                   const float* __restrict__ sums,
                                                   const float* __restrict__ g,
                                                   const float* __restrict__ bt,
                                                   const float* __restrict__ W,
                                                   ushort_t* __restrict__ hwb) {
    __shared__ ushort_t Wf[2 * 4 * 64 * 8];  // [ks][c][lane][j] bf16 fragments of W2
    __shared__ float mu_s[DD], sc_s[DD], bt_s[DD];
    int t = threadIdx.x;
    if (t < DD) {
        const float inv_n = 1.0f / (float)NN;
        float mu = sums[t] * inv_n;
        float var = sums[64 + t] * inv_n - mu * mu;
        mu_s[t] = mu;
        sc_s[t] = g[t] * rsqrtf(var + BN_EPS);
        bt_s[t] = bt[t];
    }
    for (int e = t; e < 4096; e += 256) {
        int ks = e >> 11;
        int c = (e >> 9) & 3;
        int l = (e >> 3) & 63;
        int j = e & 7;
        int k = ks * 32 + ((l >> 4) << 3) + j;
        int col = c * 16 + (l & 15);
        Wf[e] = f2bf(W[k * DD + col]);
    }
    __syncthreads();

    int w = t >> 6, l = t & 63;
    int lr = l & 15, lk = l >> 4;

#pragma unroll
    for (int gi = 0; gi < 4; ++gi) {
        long rowbase = (long)blockIdx.x * 256 + w * 64 + gi * 16;
        long r = rowbase + lr;

        bf16x8 afrag[2];
#pragma unroll
        for (int ks = 0; ks < 2; ++ks) {
            int k0 = ks * 32 + (lk << 3);
            uint4 av = (r < NN) ? *(const uint4*)(aggb + r * DD + k0)
                                : make_uint4(0, 0, 0, 0);
            float4 muA = *(const float4*)&mu_s[k0];
            float4 muB = *(const float4*)&mu_s[k0 + 4];
            float4 scA = *(const float4*)&sc_s[k0];
            float4 scB = *(const float4*)&sc_s[k0 + 4];
            float4 btA = *(const float4*)&bt_s[k0];
            float4 btB = *(const float4*)&bt_s[k0 + 4];
            float h0 = fmaxf((bflo(av.x) - muA.x) * scA.x + btA.x, 0.f);
            float h1 = fmaxf((bfhi(av.x) - muA.y) * scA.y + btA.y, 0.f);
            float h2 = fmaxf((bflo(av.y) - muA.z) * scA.z + btA.z, 0.f);
            float h3 = fmaxf((bfhi(av.y) - muA.w) * scA.w + btA.w, 0.f);
            float h4 = fmaxf((bflo(av.z) - muB.x) * scB.x + btB.x, 0.f);
            float h5 = fmaxf((bfhi(av.z) - muB.y) * scB.y + btB.y, 0.f);
            float h6 = fmaxf((bflo(av.w) - muB.z) * scB.z + btB.z, 0.f);
            float h7 = fmaxf((bfhi(av.w) - muB.w) * scB.w + btB.w, 0.f);
            bf16x8 fr;
            fr[0] = (short)f2bf(h0); fr[1] = (short)f2bf(h1);
            fr[2] = (short)f2bf(h2); fr[3] = (short)f2bf(h3);
            fr[4] = (short)f2bf(h4); fr[5] = (short)f2bf(h5);
            fr[6] = (short)f2bf(h6); fr[7] = (short)f2bf(h7);
            afrag[ks] = fr;
        }

        f32x4 acc[4];
#pragma unroll
        for (int c = 0; c < 4; ++c) acc[c] = (f32x4){0.f, 0.f, 0.f, 0.f};
#pragma unroll
        for (int c = 0; c < 4; ++c) {
#pragma unroll
            for (int ks = 0; ks < 2; ++ks) {
                bf16x8 bfr = *(bf16x8*)&Wf[((ks * 4 + c) << 9) + (l << 3)];
                acc[c] = __builtin_amdgcn_mfma_f32_16x16x32_bf16(afrag[ks], bfr, acc[c],
                                                                 0, 0, 0);
            }
        }

#pragma unroll
        for (int c = 0; c < 4; ++c) {
#pragma unroll
            for (int rr = 0; rr < 4; ++rr) {
                long orow = rowbase + lk * 4 + rr;
                if (orow < NN) hwb[orow * DD + c * 16 + lr] = f2bf(acc[c][rr]);
            }
        }
    }
}

// ------- gather-aggregate: 8 lanes/row uint4, 32 edges in flight, shfl reduce -------
template <int WAGG_BF16>
__global__ __launch_bounds__(256) void gcn_agg(const ushort_t* __restrict__ hwb,
                                               const float* __restrict__ dis,
                                               const int* __restrict__ cnt,
                                               const int* __restrict__ start,
                                               const uint_t* __restrict__ ep,
                                               const float* __restrict__ bias,
                                               void* __restrict__ aggv,
                                               float* __restrict__ sums) {
    int t = threadIdx.x;
    int w = t >> 6;
    int lane = t & 63;
    int j = lane >> 3;
    int c = lane & 7;
    float selfmask = (j == 0) ? 1.f : 0.f;

    __shared__ float ls[4][128];
    for (int k = t; k < 512; k += 256) ((float*)ls)[k] = 0.f;
    __syncthreads();

    float bs[8];
#pragma unroll
    for (int k = 0; k < 8; ++k) bs[k] = bias[8 * c + k];

    for (long n = (long)blockIdx.x * 4 + w; n < NN; n += (long)gridDim.x * 4) {
        int rs = start[n];
        int ce = cnt[n];
        float sn = dis[n];
        float sq = sn * sn;

        uint4 sv = ((const uint4*)(hwb + (long)n * DD))[c];
        float acc[8];
        acc[0] = selfmask * (bflo(sv.x) * sq + bs[0]);
        acc[1] = selfmask * (bfhi(sv.x) * sq + bs[1]);
        acc[2] = selfmask * (bflo(sv.y) * sq + bs[2]);
        acc[3] = selfmask * (bfhi(sv.y) * sq + bs[3]);
        acc[4] = selfmask * (bflo(sv.z) * sq + bs[4]);
        acc[5] = selfmask * (bfhi(sv.z) * sq + bs[5]);
        acc[6] = selfmask * (bflo(sv.w) * sq + bs[6]);
        acc[7] = selfmask * (bfhi(sv.w) * sq + bs[7]);

        for (int i = 0; i < ce; i += 32) {
            int i0 = i + j, i1 = i + 8 + j, i2 = i + 16 + j, i3 = i + 24 + j;
            uint_t u0 = (i0 < ce) ? ep[rs + i0] : 0u;
            uint_t u1 = (i1 < ce) ? ep[rs + i1] : 0u;
            uint_t u2 = (i2 < ce) ? ep[rs + i2] : 0u;
            uint_t u3 = (i3 < ce) ? ep[rs + i3] : 0u;
            uint4 q0 = ((const uint4*)(hwb + (long)(u0 & 0x1FFFF) * DD))[c];
            uint4 q1 = ((const uint4*)(hwb + (long)(u1 & 0x1FFFF) * DD))[c];
            uint4 q2 = ((const uint4*)(hwb + (long)(u2 & 0x1FFFF) * DD))[c];
            uint4 q3 = ((const uint4*)(hwb + (long)(u3 & 0x1FFFF) * DD))[c];
            float n0 = __uint_as_float((u0 >> 17) << 16);
            float n1 = __uint_as_float((u1 >> 17) << 16);
            float n2 = __uint_as_float((u2 >> 17) << 16);
            float n3 = __uint_as_float((u3 >> 17) << 16);
            acc[0] += bflo(q0.x) * n0; acc[1] += bfhi(q0.x) * n0;
            acc[2] += bflo(q0.y) * n0; acc[3] += bfhi(q0.y) * n0;
            acc[4] += bflo(q0.z) * n0; acc[5] += bfhi(q0.z) * n0;
            acc[6] += bflo(q0.w) * n0; acc[7] += bfhi(q0.w) * n0;
            acc[0] += bflo(q1.x) * n1; acc[1] += bfhi(q1.x) * n1;
            acc[2] += bflo(q1.y) * n1; acc[3] += bfhi(q1.y) * n1;
            acc[4] += bflo(q1.z) * n1; acc[5] += bfhi(q1.z) * n1;
            acc[6] += bflo(q1.w) * n1; acc[7] += bfhi(q1.w) * n1;
            acc[0] += bflo(q2.x) * n2; acc[1] += bfhi(q2.x) * n2;
            acc[2] += bflo(q2.y) * n2; acc[3] += bfhi(q2.y) * n2;
            acc[4] += bflo(q2.z) * n2; acc[5] += bfhi(q2.z) * n2;
            acc[6] += bflo(q2.w) * n2; acc[7] += bfhi(q2.w) * n2;
            acc[0] += bflo(q3.x) * n3; acc[1] += bfhi(q3.x) * n3;
            acc[2] += bflo(q3.y) * n3; acc[3] += bfhi(q3.y) * n3;
            acc[4] += bflo(q3.z) * n3; acc[5] += bfhi(q3.z) * n3;
            acc[6] += bflo(q3.w) * n3; acc[7] += bfhi(q3.w) * n3;
        }

#pragma unroll
        for (int m = 8; m < 64; m <<= 1) {
#pragma unroll
            for (int k = 0; k < 8; ++k) acc[k] += __shfl_xor(acc[k], m, 64);
        }

        if (j == 0) {
            if (WAGG_BF16) {
                uint4 pk;
                pk.x = pack2(acc[0], acc[1]);
                pk.y = pack2(acc[2], acc[3]);
                pk.z = pack2(acc[4], acc[5]);
                pk.w = pack2(acc[6], acc[7]);
                ((uint4*)((ushort_t*)aggv + (long)n * DD))[c] = pk;
            } else {
                float4* op = (float4*)((float*)aggv + (long)n * DD + 8 * c);
                op[0] = make_float4(acc[0], acc[1], acc[2], acc[3]);
                op[1] = make_float4(acc[4], acc[5], acc[6], acc[7]);
            }
#pragma unroll
            for (int k = 0; k < 8; ++k) {
                ls[w][8 * c + k] += acc[k];
                ls[w][64 + 8 * c + k] += acc[k] * acc[k];
            }
        }
    }

    __syncthreads();
    if (t < 128) {
        float a = ls[0][t] + ls[1][t] + ls[2][t] + ls[3][t];
        atomicAdd(&sums[t], a);
    }
}

// ---------------- BN2 apply + global_add_pool (batch sorted, run-length) ----------------
__global__ __launch_bounds__(256) void bn_pool(const float* __restrict__ agg,
                                               const float* __restrict__ sums,
                                               const float* __restrict__ g,
                                               const float* __restrict__ bt,
                                               const int* __restrict__ batch,
                                               float* __restrict__ out,
                                               float* __restrict__ pool) {
    int t = threadIdx.x;
    int d = t & 63, rq = t >> 6;
    const float inv_n = 1.0f / (float)NN;
    float mu = sums[d] * inv_n;
    float var = sums[64 + d] * inv_n - mu * mu;
    float sc = g[d] * rsqrtf(var + BN_EPS);
    float bd = bt[d];
    long base = (long)blockIdx.x * 256;
    float acc = 0.f;
    int cur = -1;
    for (int i = 0; i < 64; ++i) {
        long r = base + rq + 4 * i;
        if (r >= NN) break;
        int b = batch[r];
        float v = (agg[r * DD + d] - mu) * sc + bd;
        out[r * DD + d] = v;
        if (b != cur) {
            if (cur >= 0) atomicAdd(&pool[(long)cur * DD + d], acc);
            acc = 0.f;
            cur = b;
        }
        acc += v;
    }
    if (cur >= 0) atomicAdd(&pool[(long)cur * DD + d], acc);
}

extern "C" void kernel_launch(void* const* d_in, const int* in_sizes, int n_in,
                              void* d_out, int out_size, void* d_ws, size_t ws_size,
                              hipStream_t stream) {
    const float* x = (const float*)d_in[0];
    const int* ei = (const int*)d_in[1];
    const int* batch = (const int*)d_in[2];
    const float* W_embed = (const float*)d_in[3];
    const float* W1 = (const float*)d_in[4];
    const float* b1 = (const float*)d_in[5];
    const float* g1 = (const float*)d_in[6];
    const float* bt1 = (const float*)d_in[7];
    const float* W2 = (const float*)d_in[8];
    const float* b2 = (const float*)d_in[9];
    const float* g2 = (const float*)d_in[10];
    const float* bt2 = (const float*)d_in[11];

    const int* src = ei;
    const int* dst = ei + NE;

    float* out = (float*)d_out;         // h: N*DD
    float* pool = out + (long)NN * DD;  // h_pool: NG*DD

    const long ND = (long)NN * DD;

    // workspace layout (cnt,cursor contiguous for single zero pass)
    char* w = (char*)d_ws;
    int* cnt = (int*)w;           w += sizeof(int) * NN;
    int* cursor = (int*)w;        w += sizeof(int) * 4;
    int* start = (int*)w;         w += sizeof(int) * NN;
    float* dis = (float*)w;       w += sizeof(float) * NN;
    float* sums1 = (float*)w;     w += sizeof(float) * 128;  // sums1+sums2 contiguous
    float* sums2 = (float*)w;     w += sizeof(float) * 128;
    int* rank = (int*)w;          w += sizeof(int) * NE;
    uint_t* ep = (uint_t*)w;      w += sizeof(uint_t) * NE;
    ushort_t* hwb = (ushort_t*)w; w += sizeof(ushort_t) * ND;
    ushort_t* agg1b = (ushort_t*)w; w += sizeof(ushort_t) * ND;
    float* aggbuf = (float*)w;    /* += sizeof(float) * ND */

    dim3 blk(256);
    const int nbN = (NN + 255) / 256;
    const int nbE = (NE + 255) / 256;
    const long n_ints = (long)NN + 4;

    // ---- CSR build + norms (single atomic pass; fill is atomic-free) ----
    init_k<<<dim3((int)((n_ints + 255) / 256)), blk, 0, stream>>>(cnt, n_ints, pool, sums1);
    deg_rank<<<dim3(nbE), blk, 0, stream>>>(dst, cnt, rank);
    alloc_k<<<dim3(nbN), blk, 0, stream>>>(cnt, start, cursor, dis);
    fill_edges<<<dim3(nbE), blk, 0, stream>>>(src, dst, rank, dis, start, ep);

    // ---- hw1 = x @ (W_embed @ W1) (bf16) ----
    mm1_k<<<dim3(nbN), blk, 0, stream>>>(x, W_embed, W1, hwb);

    // ---- layer 1 (agg -> bf16, stats -> sums1) ----
    gcn_agg<1><<<dim3(AGG_BLOCKS), blk, 0, stream>>>(hwb, dis, cnt, start, ep, b1,
                                                     (void*)agg1b, sums1);

    // ---- BN1+ReLU fused into layer-2 matmul (MFMA) ----
    mm2_bn_mfma<<<dim3(nbN), blk, 0, stream>>>(agg1b, sums1, g1, bt1, W2, hwb);

    // ---- layer 2 (agg -> f32, stats -> sums2) ----
    gcn_agg<0><<<dim3(AGG_BLOCKS), blk, 0, stream>>>(hwb, dis, cnt, start, ep, b2,
                                                     (void*)aggbuf, sums2);

    // ---- BN2 + write h + pool ----
    bn_pool<<<dim3(nbN), blk, 0, stream>>>(aggbuf, sums2, g2, bt2, batch, out, pool);
}